// Round 3
// baseline (878.438 us; speedup 1.0000x reference)
//
#include <hip/hip_runtime.h>
#include <hip/hip_bf16.h>

// Problem constants (B=32, D=256, H=W=64, K=6, CTX=256, TEMP=0.5)
#define NB 32
#define ND 256
#define NN_ 4096
#define NK 6

__device__ __forceinline__ float bf2f(unsigned int u) {
    union { unsigned int i; float f; } v; v.i = (u & 0xffffu) << 16; return v.f;
}
__device__ __forceinline__ unsigned short f2bf(float f) {
    __hip_bfloat16 h = __float2bfloat16(f);
    return *reinterpret_cast<unsigned short*>(&h);
}
__device__ __forceinline__ float gelu_exact(float x) {
    return 0.5f * x * (1.0f + erff(x * 0.70710678118654752f));
}

// Coalesced cooperative matvec chunk: 16 lanes per row. Lane l covers
// x[l*16 .. l*16+16); returns the FULL row dot in all 16 lanes of the group.
// Per load instruction: 16 consecutive lanes read 256 B contiguous.
__device__ __forceinline__ float mv16(const float* __restrict__ W, int stride,
                                      int row, int l, const float* xs) {
    const float4* wr = reinterpret_cast<const float4*>(W + (size_t)row * stride + l * 16);
    const float4* xv = reinterpret_cast<const float4*>(xs + l * 16);
    float acc = 0.f;
#pragma unroll
    for (int i = 0; i < 4; ++i) {
        float4 w = wr[i], x = xv[i];
        acc += w.x * x.x + w.y * x.y + w.z * x.z + w.w * x.w;
    }
    acc += __shfl_xor(acc, 1, 64);
    acc += __shfl_xor(acc, 2, 64);
    acc += __shfl_xor(acc, 4, 64);
    acc += __shfl_xor(acc, 8, 64);
    return acc;
}

// ---------------- setup: init mask/accs/state, kwt = k_w^T, sw1p padded copy,
// context MLP + q for step 0 (all matvecs 16-lane coalesced) ----------------
__global__ void k_setup(float* __restrict__ mask, float* __restrict__ accs,
                        float* __restrict__ state, float* __restrict__ kwt,
                        const float* __restrict__ k_w,
                        const float* __restrict__ sw1, float* __restrict__ sw1p,
                        const float* __restrict__ tc, const float* __restrict__ w1,
                        const float* __restrict__ b1, const float* __restrict__ w2,
                        const float* __restrict__ b2, float* __restrict__ clue,
                        const float* __restrict__ qn_g, const float* __restrict__ qn_b,
                        const float* __restrict__ q_w, const float* __restrict__ q_b,
                        float* __restrict__ qbuf) {
    __shared__ __align__(16) float tcs[256];
    __shared__ __align__(16) float h1[256];
    __shared__ __align__(16) float c0sh[256];
    __shared__ float sred[8];
    int blk = blockIdx.x, t = threadIdx.x;
    if (blk < 935) {
        int i = blk * 256 + t;
        if (i < 131072) mask[i] = 1.f;
        else if (i < 131840) accs[i - 131072] = 0.f;     // [6][4][32]
        else if (i < 140032) state[i - 131840] = 0.f;    // [32][256] h(0)=0
        else if (i < 205568) {
            int j = i - 140032;                          // kwt[j>>8][j&255] = k_w[(j&255)][j>>8]
            kwt[j] = k_w[(size_t)(j & 255) * 256 + (j >> 8)];
        } else {
            int j = i - 205568;                          // sw1p[128][264], 16B-aligned rows
            int row = j / 264, col = j - row * 264;
            sw1p[j] = (col < 257) ? sw1[row * 257 + col] : 0.f;
        }
        return;
    }
    int b = blk - 935;
    int lane = t & 63, wv = t >> 6, l = t & 15, rq = t >> 4;
    tcs[t] = tc[b * 256 + t];
    __syncthreads();
    // h1 = gelu(w1 @ tc + b1)
#pragma unroll 4
    for (int bi = 0; bi < 16; ++bi) {
        int row = bi * 16 + rq;
        float acc = mv16(w1, 256, row, l, tcs) + b1[row];
        if (l == 0) h1[row] = gelu_exact(acc);
    }
    __syncthreads();
    // clue rows (1536)
#pragma unroll 2
    for (int bi = 0; bi < 96; ++bi) {
        int row = bi * 16 + rq;
        float a2 = mv16(w2, 256, row, l, h1) + b2[row];
        float cv = fminf(fmaxf(a2, -10.f), 10.f);
        if (l == 0) {
            clue[b * 1536 + row] = cv;
            if (row < 256) c0sh[row] = cv;
        }
    }
    __syncthreads();
    // LN(clue0 + 0) -> q0
    float x0 = c0sh[t];
    float s = x0, s2 = x0 * x0;
#pragma unroll
    for (int off = 32; off > 0; off >>= 1) {
        s += __shfl_down(s, off, 64);
        s2 += __shfl_down(s2, off, 64);
    }
    if (lane == 0) { sred[wv] = s; sred[4 + wv] = s2; }
    __syncthreads();
    float mu = (sred[0] + sred[1] + sred[2] + sred[3]) * (1.f / 256.f);
    float var = (sred[4] + sred[5] + sred[6] + sred[7]) * (1.f / 256.f) - mu * mu;
    float rs = rsqrtf(var + 1e-5f);
    __syncthreads();
    tcs[t] = (x0 - mu) * rs * qn_g[t] + qn_b[t];     // reuse tcs as qln
    __syncthreads();
#pragma unroll 4
    for (int bi = 0; bi < 16; ++bi) {
        int row = bi * 16 + rq;
        float qv = mv16(q_w, 256, row, l, tcs) + q_b[row];
        if (l == 0) qbuf[b * 256 + row] = qv;
    }
}

// ---------------- fused transpose + LN -> ft (bf16, row-major [b][n][256]) ----------
// Read side: consecutive lanes walk contiguous n (1 KB contiguous per instr per dq
// group). d-reduction via shfl(16,32) + cross-wave LDS. Coalesced 512 B row writeout.
// tile==64 blocks: q'0 = kwt @ q0 and qct0 = q0 . k_b for step 0.
__global__ __launch_bounds__(256, 4) void k_ln(
    const float* __restrict__ features, const float* __restrict__ fn_g,
    const float* __restrict__ fn_b, unsigned short* __restrict__ ft,
    const float* __restrict__ qbuf, const float* __restrict__ kwt,
    const float* __restrict__ k_b, float* __restrict__ qpr,
    float* __restrict__ qct) {
    int tile = blockIdx.x, b = blockIdx.y, t = threadIdx.x;
    int lane = t & 63, wv = t >> 6, l = t & 15;
    __shared__ __align__(16) unsigned short A[64 * 264];   // padded rows
    __shared__ __align__(16) float redS[4][16][8];
    __shared__ __align__(16) float qs[256];
    __shared__ float sred[4];
    unsigned int* A32 = reinterpret_cast<unsigned int*>(A);

    if (tile == 64) {   // q' for step 0
        int rq = t >> 4;
        qs[t] = qbuf[b * 256 + t];
        __syncthreads();
#pragma unroll 4
        for (int bi = 0; bi < 16; ++bi) {
            int row = bi * 16 + rq;
            float qp = mv16(kwt, 256, row, l, qs);
            if (l == 0) qpr[b * 256 + row] = qp;
        }
        float ct = qs[t] * k_b[t];
#pragma unroll
        for (int off = 32; off > 0; off >>= 1) ct += __shfl_down(ct, off, 64);
        if (lane == 0) sred[wv] = ct;
        __syncthreads();
        if (t == 0) qct[b] = sred[0] + sred[1] + sred[2] + sred[3];
        return;
    }

    int n0 = tile * 64, dq = t >> 4;          // lane n-group l: n = n0 + l*4 + k
    const float* fb = features + (size_t)b * 1048576 + (size_t)dq * 16 * 4096 + n0 + l * 4;
    unsigned int u[4][8];                      // [n k][d-pair] bf16x2, d = dq*16 + 2j(+1)
    float s[4] = {0, 0, 0, 0}, s2[4] = {0, 0, 0, 0};
#pragma unroll
    for (int p = 0; p < 16; ++p) {
        float4 v = *reinterpret_cast<const float4*>(fb + (size_t)p * 4096);
        s[0] += v.x; s2[0] += v.x * v.x;
        s[1] += v.y; s2[1] += v.y * v.y;
        s[2] += v.z; s2[2] += v.z * v.z;
        s[3] += v.w; s2[3] += v.w * v.w;
        unsigned int b0 = f2bf(v.x), b1_ = f2bf(v.y), b2_ = f2bf(v.z), b3_ = f2bf(v.w);
        if ((p & 1) == 0) {
            u[0][p >> 1] = b0; u[1][p >> 1] = b1_; u[2][p >> 1] = b2_; u[3][p >> 1] = b3_;
        } else {
            u[0][p >> 1] |= b0 << 16; u[1][p >> 1] |= b1_ << 16;
            u[2][p >> 1] |= b2_ << 16; u[3][p >> 1] |= b3_ << 16;
        }
    }
    // reduce over dq: lane bits 4,5 in-wave, then cross-wave via LDS
#pragma unroll
    for (int k = 0; k < 4; ++k) {
        s[k]  += __shfl_xor(s[k], 16, 64);  s[k]  += __shfl_xor(s[k], 32, 64);
        s2[k] += __shfl_xor(s2[k], 16, 64); s2[k] += __shfl_xor(s2[k], 32, 64);
    }
    if (lane < 16) {
        *reinterpret_cast<float4*>(&redS[wv][lane][0]) = make_float4(s[0], s[1], s[2], s[3]);
        *reinterpret_cast<float4*>(&redS[wv][lane][4]) = make_float4(s2[0], s2[1], s2[2], s2[3]);
    }
    __syncthreads();
    float mm[4], rr[4];
#pragma unroll
    for (int k = 0; k < 4; ++k) {
        float ts_ = redS[0][l][k] + redS[1][l][k] + redS[2][l][k] + redS[3][l][k];
        float t2  = redS[0][l][4 + k] + redS[1][l][4 + k] + redS[2][l][4 + k] + redS[3][l][4 + k];
        float mean = ts_ * (1.f / 256.f);
        float var = t2 * (1.f / 256.f) - mean * mean;
        mm[k] = mean; rr[k] = rsqrtf(var + 1e-5f);
    }
    float gg[16], ee[16];
#pragma unroll
    for (int j4 = 0; j4 < 4; ++j4) {
        *reinterpret_cast<float4*>(&gg[j4 * 4]) =
            *reinterpret_cast<const float4*>(fn_g + dq * 16 + j4 * 4);
        *reinterpret_cast<float4*>(&ee[j4 * 4]) =
            *reinterpret_cast<const float4*>(fn_b + dq * 16 + j4 * 4);
    }
#pragma unroll
    for (int k = 0; k < 4; ++k) {
        int rowl = l * 4 + k;
        unsigned int w[8];
#pragma unroll
        for (int j = 0; j < 8; ++j) {
            float x0 = bf2f(u[k][j]), x1 = bf2f(u[k][j] >> 16);
            unsigned int lo = f2bf((x0 - mm[k]) * rr[k] * gg[2 * j] + ee[2 * j]);
            unsigned int hi = f2bf((x1 - mm[k]) * rr[k] * gg[2 * j + 1] + ee[2 * j + 1]);
            w[j] = lo | (hi << 16);
        }
        uint4* dst = reinterpret_cast<uint4*>(&A32[rowl * 132 + dq * 8]);
        dst[0] = make_uint4(w[0], w[1], w[2], w[3]);
        dst[1] = make_uint4(w[4], w[5], w[6], w[7]);
    }
    __syncthreads();
    // writeout: coalesced 512 B rows
    int ch = t & 31, rw = t >> 5;
    unsigned short* dst = ft + ((size_t)b * 4096 + n0) * 256;
#pragma unroll
    for (int ps = 0; ps < 8; ++ps) {
        int row = ps * 8 + rw;
        uint4 vv = *reinterpret_cast<const uint4*>(&A[row * 264 + ch * 8]);
        *reinterpret_cast<uint4*>(dst + (size_t)row * 256 + ch * 8) = vv;
    }
}

// ---------------- B: single pass over ft: scores (e) + Sigma e*f partials.
// c==32 blocks emit previous step's stop-logit + centroid outputs. ----------------
__global__ __launch_bounds__(256, 4) void k_score(
    const float* __restrict__ qpr, const float* __restrict__ qct,
    const unsigned short* __restrict__ ft, const float* __restrict__ mask,
    float* __restrict__ escore, float* __restrict__ accs,
    float* __restrict__ pbuf, const float* __restrict__ attbuf,
    const float* __restrict__ sw1p, const float* __restrict__ sb1,
    const float* __restrict__ sw2, const float* __restrict__ sb2,
    float* __restrict__ out_cent, float* __restrict__ out_stop, int kstep) {
    int c = blockIdx.x, b = blockIdx.y, t = threadIdx.x;
    int lane = t & 63, wv = t >> 6;
    __shared__ __align__(16) float qs[256];
    __shared__ __align__(16) float part2[4][256];
    __shared__ float sred[8];
    if (c == 32) {   // stop head + centroid out for step kstep-1
        if (kstep == 0) return;
        int kp_ = kstep - 1;
        qs[t] = attbuf[b * 256 + t];
        __syncthreads();
        float entv = -accs[kp_ * 128 + 96 + b] * 0.12022458674074826f; // 1/log(4096+1e-6)
        int sl = t & 15, srq = t >> 4;
        float vsum = 0.f;
#pragma unroll 2
        for (int bi = 0; bi < 8; ++bi) {
            int row = bi * 16 + srq;
            float acc = mv16(sw1p, 264, row, sl, qs);
            acc += sb1[row] + entv * sw1p[row * 264 + 256];
            vsum += gelu_exact(acc) * sw2[row];
        }
        vsum *= 0.0625f;   // each row counted by 16 lanes
#pragma unroll
        for (int off = 32; off > 0; off >>= 1) vsum += __shfl_down(vsum, off, 64);
        if (lane == 0) sred[wv] = vsum;
        __syncthreads();
        if (t == 0) {
            float sraw = sb2[0] + sred[0] + sred[1] + sred[2] + sred[3];
            out_stop[b * 6 + kp_] = 4.f * tanhf(sraw * 0.25f);
            out_cent[(b * 6 + kp_) * 2 + 0] = accs[kp_ * 128 + 32 + b];
            out_cent[(b * 6 + kp_) * 2 + 1] = accs[kp_ * 128 + 64 + b];
        }
        return;
    }
    qs[t] = qpr[b * 256 + t];
    __syncthreads();
    int l = t & 15, rg = t >> 4;        // 16 lanes per row, 16 row-groups
    float qq[16];
#pragma unroll
    for (int i = 0; i < 16; ++i) qq[i] = qs[l * 16 + i];
    float qc = qct[b];
    float acc[16];
#pragma unroll
    for (int i = 0; i < 16; ++i) acc[i] = 0.f;
    float dsum = 0.f;
    const unsigned short* fb = ft + ((size_t)b * 4096 + c * 128) * 256 + l * 16;
#pragma unroll 2
    for (int rr = 0; rr < 8; ++rr) {
        int nl = rr * 16 + rg;
        int n = c * 128 + nl;
        const uint4* p = reinterpret_cast<const uint4*>(fb + (size_t)nl * 256);
        uint4 r0 = p[0], r1 = p[1];
        float v[16];
        v[0]  = bf2f(r0.x); v[1]  = bf2f(r0.x >> 16);
        v[2]  = bf2f(r0.y); v[3]  = bf2f(r0.y >> 16);
        v[4]  = bf2f(r0.z); v[5]  = bf2f(r0.z >> 16);
        v[6]  = bf2f(r0.w); v[7]  = bf2f(r0.w >> 16);
        v[8]  = bf2f(r1.x); v[9]  = bf2f(r1.x >> 16);
        v[10] = bf2f(r1.y); v[11] = bf2f(r1.y >> 16);
        v[12] = bf2f(r1.z); v[13] = bf2f(r1.z >> 16);
        v[14] = bf2f(r1.w); v[15] = bf2f(r1.w >> 16);
        float dot = 0.f;
#pragma unroll
        for (int i = 0; i < 16; ++i) dot += v[i] * qq[i];
        dot += __shfl_xor(dot, 1, 64);
        dot += __shfl_xor(dot, 2, 64);
        dot += __shfl_xor(dot, 4, 64);
        dot += __shfl_xor(dot, 8, 64);
        float sc = (dot + qc) * 0.0625f + logf(mask[(size_t)b * 4096 + n]);
        sc = fminf(fmaxf(sc, -50.f), 50.f);
        float lg = fminf(fmaxf(sc * 2.f, -50.f), 50.f);   // /TEMP, TEMP=0.5
        float e = expf(lg);
        if (l == 0) escore[(size_t)b * 4096 + n] = e;
        dsum += e;
#pragma unroll
        for (int i = 0; i < 16; ++i) acc[i] += e * v[i];
    }
    // reduce acc across the wave's 4 row-groups (lane bits 4,5)
#pragma unroll
    for (int i = 0; i < 16; ++i) {
        acc[i] += __shfl_xor(acc[i], 16, 64);
        acc[i] += __shfl_xor(acc[i], 32, 64);
    }
    if (lane < 16) {
#pragma unroll
        for (int i4 = 0; i4 < 4; ++i4)
            *reinterpret_cast<float4*>(&part2[wv][lane * 16 + i4 * 4]) =
                make_float4(acc[i4 * 4], acc[i4 * 4 + 1], acc[i4 * 4 + 2], acc[i4 * 4 + 3]);
    }
    dsum *= 0.0625f;   // each e counted by 16 lanes
#pragma unroll
    for (int off = 32; off > 0; off >>= 1) dsum += __shfl_down(dsum, off, 64);
    if (lane == 0) sred[wv] = dsum;
    __syncthreads();
    if (t == 0) atomicAdd(&accs[kstep * 128 + b], sred[0] + sred[1] + sred[2] + sred[3]);
    float sum = part2[0][t] + part2[1][t] + part2[2][t] + part2[3][t];
    pbuf[((size_t)c * 32 + b) * 256 + t] = sum;
}

// ---------------- C: amap/centroid/entropy/mask (128 blk) + GRU block per b:
// attended = v_w @ abar + v_b; GRU -> h; LN -> q; q' = kwt @ q (all 16-lane mv) ----
__global__ __launch_bounds__(256, 4) void k_attn2gate(
    const float* __restrict__ escore, float* __restrict__ mask,
    float* __restrict__ accs, float* __restrict__ out_amap,
    const float* __restrict__ pbuf, float* __restrict__ state,
    const float* __restrict__ clue,
    const float* __restrict__ qn_g, const float* __restrict__ qn_b,
    const float* __restrict__ q_w, const float* __restrict__ q_b,
    const float* __restrict__ v_w, const float* __restrict__ v_b,
    const float* __restrict__ wih, const float* __restrict__ bih,
    const float* __restrict__ whh, const float* __restrict__ bhh,
    const float* __restrict__ kwt, const float* __restrict__ k_b,
    float* __restrict__ attbuf, float* __restrict__ qpr,
    float* __restrict__ qct, int kstep) {
    int bb = blockIdx.x, t = threadIdx.x;
    int lane = t & 63, wv = t >> 6;
    __shared__ __align__(16) float att[256];
    __shared__ __align__(16) float st[256];
    __shared__ __align__(16) float atv[256];
    __shared__ __align__(16) float gish[768];
    __shared__ __align__(16) float ghsh[768];
    __shared__ float sred[12];
    if (bb < 128) {
        int b = bb & 31, c = bb >> 5;
        int n4 = (c * 256 + t) * 4;
        float inv = 1.f / accs[kstep * 128 + b];
        float4 e4 = *reinterpret_cast<const float4*>(&escore[(size_t)b * 4096 + n4]);
        float4 m4 = *reinterpret_cast<const float4*>(&mask[(size_t)b * 4096 + n4]);
        float a[4] = {fmaxf(e4.x * inv, 1e-8f), fmaxf(e4.y * inv, 1e-8f),
                      fmaxf(e4.z * inv, 1e-8f), fmaxf(e4.w * inv, 1e-8f)};
        *reinterpret_cast<float4*>(&out_amap[((size_t)(b * 6 + kstep)) * 4096 + n4])
            = make_float4(a[0], a[1], a[2], a[3]);
        float mv[4] = {m4.x, m4.y, m4.z, m4.w};
        float s0 = 0.f, s1 = 0.f, s2 = 0.f;
#pragma unroll
        for (int j = 0; j < 4; ++j) {
            int n = n4 + j;
            s0 += a[j] * (float)(n >> 6);
            s1 += a[j] * (float)(n & 63);
            float ac = fmaxf(a[j], 1e-6f);
            s2 += ac * logf(ac);
            mv[j] = fmaxf(mv[j] * (1.f - 0.9f * a[j]), 1e-6f);
        }
        *reinterpret_cast<float4*>(&mask[(size_t)b * 4096 + n4])
            = make_float4(mv[0], mv[1], mv[2], mv[3]);
#pragma unroll
        for (int off = 32; off > 0; off >>= 1) {
            s0 += __shfl_down(s0, off, 64);
            s1 += __shfl_down(s1, off, 64);
            s2 += __shfl_down(s2, off, 64);
        }
        if (lane == 0) { sred[wv] = s0; sred[4 + wv] = s1; sred[8 + wv] = s2; }
        __syncthreads();
        if (t == 0) {
            atomicAdd(&accs[kstep * 128 + 32 + b], sred[0] + sred[1] + sred[2] + sred[3]);
            atomicAdd(&accs[kstep * 128 + 64 + b], sred[4] + sred[5] + sred[6] + sred[7]);
            atomicAdd(&accs[kstep * 128 + 96 + b], sred[8] + sred[9] + sred[10] + sred[11]);
        }
        return;
    }
    int b = bb - 128;
    int l = t & 15, rq = t >> 4;
    float inv = 1.f / accs[kstep * 128 + b];
    float a = 0.f;
#pragma unroll
    for (int c2 = 0; c2 < 32; ++c2) a += pbuf[((size_t)c2 * 32 + b) * 256 + t];
    att[t] = a * inv;            // abar
    __syncthreads();
    // attended = v_w @ abar + v_b
#pragma unroll 4
    for (int bi = 0; bi < 16; ++bi) {
        int row = bi * 16 + rq;
        float at = mv16(v_w, 256, row, l, att) + v_b[row];
        if (l == 0) { atv[row] = at; attbuf[b * 256 + row] = at; }
    }
    __syncthreads();
    if (kstep == 5) return;
    float hprev = state[b * 256 + t];
    st[t] = hprev;
    __syncthreads();
    // GRU gates: gi = wih @ attended + bih, gh = whh @ h + bhh (768 rows each)
#pragma unroll 2
    for (int bi = 0; bi < 48; ++bi) {
        int row = bi * 16 + rq;
        float gi_ = mv16(wih, 256, row, l, atv) + bih[row];
        float gh_ = mv16(whh, 256, row, l, st) + bhh[row];
        if (l == 0) { gish[row] = gi_; ghsh[row] = gh_; }
    }
    __syncthreads();
    float rr_ = 1.f / (1.f + expf(-(gish[t] + ghsh[t])));
    float zz = 1.f / (1.f + expf(-(gish[256 + t] + ghsh[256 + t])));
    float nn = tanhf(gish[512 + t] + rr_ * ghsh[512 + t]);
    float h = (1.f - zz) * nn + zz * hprev;
    state[b * 256 + t] = h;
    // LN(clue_{k+1} + h)
    float x = clue[((size_t)b * 6 + kstep + 1) * 256 + t] + h;
    float s = x, s2v = x * x;
#pragma unroll
    for (int off = 32; off > 0; off >>= 1) {
        s += __shfl_down(s, off, 64);
        s2v += __shfl_down(s2v, off, 64);
    }
    if (lane == 0) { sred[wv] = s; sred[4 + wv] = s2v; }
    __syncthreads();
    float mu = (sred[0] + sred[1] + sred[2] + sred[3]) * (1.f / 256.f);
    float var = (sred[4] + sred[5] + sred[6] + sred[7]) * (1.f / 256.f) - mu * mu;
    float rs = rsqrtf(var + 1e-5f);
    __syncthreads();
    att[t] = (x - mu) * rs * qn_g[t] + qn_b[t];   // qln
    __syncthreads();
    // q = q_w @ qln + q_b
#pragma unroll 4
    for (int bi = 0; bi < 16; ++bi) {
        int row = bi * 16 + rq;
        float qv = mv16(q_w, 256, row, l, att) + q_b[row];
        if (l == 0) st[row] = qv;
    }
    __syncthreads();
    float ct = st[t] * k_b[t];
#pragma unroll
    for (int off = 32; off > 0; off >>= 1) ct += __shfl_down(ct, off, 64);
    if (lane == 0) sred[8 + wv] = ct;
    // q' = kwt @ q
#pragma unroll 4
    for (int bi = 0; bi < 16; ++bi) {
        int row = bi * 16 + rq;
        float qp = mv16(kwt, 256, row, l, st);
        if (l == 0) qpr[b * 256 + row] = qp;
    }
    __syncthreads();
    if (t == 0) qct[b] = sred[8] + sred[9] + sred[10] + sred[11];
}

// ---------------- tail: stop head + centroid out for step 5 ----------------
__global__ void k_stop5(const float* __restrict__ attbuf, const float* __restrict__ accs,
                        const float* __restrict__ sw1p, const float* __restrict__ sb1,
                        const float* __restrict__ sw2, const float* __restrict__ sb2,
                        float* __restrict__ out_cent, float* __restrict__ out_stop) {
    int b = blockIdx.x, t = threadIdx.x;
    int lane = t & 63, wv = t >> 6;
    __shared__ __align__(16) float att[256];
    __shared__ float sred[4];
    att[t] = attbuf[b * 256 + t];
    __syncthreads();
    float entv = -accs[5 * 128 + 96 + b] * 0.12022458674074826f;
    int sl = t & 15, srq = t >> 4;
    float vsum = 0.f;
#pragma unroll 2
    for (int bi = 0; bi < 8; ++bi) {
        int row = bi * 16 + srq;
        float acc = mv16(sw1p, 264, row, sl, att);
        acc += sb1[row] + entv * sw1p[row * 264 + 256];
        vsum += gelu_exact(acc) * sw2[row];
    }
    vsum *= 0.0625f;
#pragma unroll
    for (int off = 32; off > 0; off >>= 1) vsum += __shfl_down(vsum, off, 64);
    if (lane == 0) sred[wv] = vsum;
    __syncthreads();
    if (t == 0) {
        float sraw = sb2[0] + sred[0] + sred[1] + sred[2] + sred[3];
        out_stop[b * 6 + 5] = 4.f * tanhf(sraw * 0.25f);
        out_cent[(b * 6 + 5) * 2 + 0] = accs[5 * 128 + 32 + b];
        out_cent[(b * 6 + 5) * 2 + 1] = accs[5 * 128 + 64 + b];
    }
}

extern "C" void kernel_launch(void* const* d_in, const int* in_sizes, int n_in,
                              void* d_out, int out_size, void* d_ws, size_t ws_size,
                              hipStream_t stream) {
    const float* features     = (const float*)d_in[0];
    const float* task_context = (const float*)d_in[1];
    const float* ctx_w1 = (const float*)d_in[2];
    const float* ctx_b1 = (const float*)d_in[3];
    const float* ctx_w2 = (const float*)d_in[4];
    const float* ctx_b2 = (const float*)d_in[5];
    const float* q_w = (const float*)d_in[6];
    const float* q_b = (const float*)d_in[7];
    const float* k_w = (const float*)d_in[8];
    const float* k_b = (const float*)d_in[9];
    const float* v_w = (const float*)d_in[10];
    const float* v_b = (const float*)d_in[11];
    const float* qn_g = (const float*)d_in[12];
    const float* qn_b = (const float*)d_in[13];
    const float* fn_g = (const float*)d_in[14];
    const float* fn_b = (const float*)d_in[15];
    const float* stop_w1 = (const float*)d_in[16];
    const float* stop_b1 = (const float*)d_in[17];
    const float* stop_w2 = (const float*)d_in[18];
    const float* stop_b2 = (const float*)d_in[19];
    const float* gru_wih = (const float*)d_in[20];
    const float* gru_bih = (const float*)d_in[21];
    const float* gru_whh = (const float*)d_in[22];
    const float* gru_bhh = (const float*)d_in[23];

    // workspace layout (~67 MB)
    unsigned short* ft = (unsigned short*)d_ws;          // [32][4096][256] bf16
    float* kwt   = (float*)(ft + (size_t)NB * NN_ * ND); // [256][256]
    float* sw1p  = kwt + 65536;                          // [128][264] padded stop_w1
    float* clue  = sw1p + 128 * 264;                     // [32][6][256]
    float* state = clue + NB * NK * ND;                  // [32][256]
    float* qbuf  = state + NB * ND;                      // [32][256]
    float* qpr   = qbuf + NB * ND;                       // [32][256]
    float* qct   = qpr + NB * ND;                        // [32]
    float* attbuf= qct + NB;                             // [32][256]
    float* mask  = attbuf + NB * ND;                     // [32][4096]
    float* escore= mask + NB * NN_;                      // [32][4096]
    float* accs  = escore + NB * NN_;                    // [6][4][32]
    float* pbuf  = accs + NK * 4 * NB;                   // [32 c][32 b][256]

    float* out_cent = (float*)d_out;          // (B,K,2)
    float* out_amap = out_cent + NB * NK * 2; // (B,K,H,W)
    float* out_stop = out_amap + (size_t)NB * NK * NN_; // (B,K)

    k_setup<<<967, 256, 0, stream>>>(mask, accs, state, kwt, k_w, stop_w1, sw1p,
                                     task_context, ctx_w1, ctx_b1, ctx_w2, ctx_b2, clue,
                                     qn_g, qn_b, q_w, q_b, qbuf);
    k_ln<<<dim3(65, 32), 256, 0, stream>>>(features, fn_g, fn_b, ft, qbuf, kwt, k_b, qpr, qct);
    for (int k = 0; k < NK; ++k) {
        k_score<<<dim3(33, 32), 256, 0, stream>>>(qpr, qct, ft, mask, escore, accs,
                                                  pbuf, attbuf,
                                                  sw1p, stop_b1, stop_w2, stop_b2,
                                                  out_cent, out_stop, k);
        k_attn2gate<<<160, 256, 0, stream>>>(escore, mask, accs, out_amap, pbuf, state,
                                             clue, qn_g, qn_b, q_w, q_b, v_w, v_b,
                                             gru_wih, gru_bih, gru_whh, gru_bhh,
                                             kwt, k_b, attbuf, qpr, qct, k);
    }
    k_stop5<<<32, 256, 0, stream>>>(attbuf, accs, sw1p, stop_b1, stop_w2, stop_b2,
                                    out_cent, out_stop);
}

// Round 4
// 871.457 us; speedup vs baseline: 1.0080x; 1.0080x over previous
//
#include <hip/hip_runtime.h>
#include <hip/hip_bf16.h>

// Problem constants (B=32, D=256, H=W=64, K=6, CTX=256, TEMP=0.5)
#define NB 32
#define ND 256
#define NN_ 4096
#define NK 6

__device__ __forceinline__ float bf2f(unsigned int u) {
    union { unsigned int i; float f; } v; v.i = (u & 0xffffu) << 16; return v.f;
}
__device__ __forceinline__ unsigned short f2bf(float f) {
    __hip_bfloat16 h = __float2bfloat16(f);
    return *reinterpret_cast<unsigned short*>(&h);
}
__device__ __forceinline__ float gelu_exact(float x) {
    return 0.5f * x * (1.0f + erff(x * 0.70710678118654752f));
}

// Coalesced cooperative matvec chunk: 16 lanes per row; full row dot in all 16 lanes.
__device__ __forceinline__ float mv16(const float* __restrict__ W, int stride,
                                      int row, int l, const float* xs) {
    const float4* wr = reinterpret_cast<const float4*>(W + (size_t)row * stride + l * 16);
    const float4* xv = reinterpret_cast<const float4*>(xs + l * 16);
    float acc = 0.f;
#pragma unroll
    for (int i = 0; i < 4; ++i) {
        float4 w = wr[i], x = xv[i];
        acc += w.x * x.x + w.y * x.y + w.z * x.z + w.w * x.w;
    }
    acc += __shfl_xor(acc, 1, 64);
    acc += __shfl_xor(acc, 2, 64);
    acc += __shfl_xor(acc, 4, 64);
    acc += __shfl_xor(acc, 8, 64);
    return acc;
}

// ---------------- setup: init buffers, tiled kwt=k_w^T, sw1p pad copy,
// context MLP over 192 blocks (b x 6 row-chunks), q0 in chunk-0 blocks ----------------
__global__ void k_setup(float* __restrict__ mask, float* __restrict__ accs,
                        float* __restrict__ state, float* __restrict__ kwt,
                        const float* __restrict__ k_w,
                        const float* __restrict__ sw1, float* __restrict__ sw1p,
                        const float* __restrict__ tc, const float* __restrict__ w1,
                        const float* __restrict__ b1, const float* __restrict__ w2,
                        const float* __restrict__ b2, float* __restrict__ clue,
                        const float* __restrict__ qn_g, const float* __restrict__ qn_b,
                        const float* __restrict__ q_w, const float* __restrict__ q_b,
                        float* __restrict__ qbuf) {
    int blk = blockIdx.x, t = threadIdx.x;
    if (blk < 128) {   // mask = 1
        reinterpret_cast<float4*>(mask)[blk * 256 + t] = make_float4(1.f, 1.f, 1.f, 1.f);
        return;
    }
    if (blk == 128) {  // accs [6][4][32] = 768 floats
        if (t < 192) reinterpret_cast<float4*>(accs)[t] = make_float4(0.f, 0.f, 0.f, 0.f);
        return;
    }
    if (blk < 137) {   // state [32][256]
        reinterpret_cast<float4*>(state)[(blk - 129) * 256 + t] = make_float4(0.f, 0.f, 0.f, 0.f);
        return;
    }
    if (blk < 170) {   // sw1p [128][264] padded copy of sw1 [128][257]
        int f4 = (blk - 137) * 256 + t;
        int j = f4 * 4, row = j / 264, col = j - row * 264;
        float v[4];
#pragma unroll
        for (int e = 0; e < 4; ++e) {
            int cc = col + e;
            v[e] = (cc < 257) ? sw1[row * 257 + cc] : 0.f;
        }
        *reinterpret_cast<float4*>(sw1p + j) = make_float4(v[0], v[1], v[2], v[3]);
        return;
    }
    if (blk < 186) {   // kwt = k_w^T via 64x64 LDS tiles (coalesced both sides)
        __shared__ float tile[64][65];
        int tt = blk - 170, ti = tt >> 2, tj = tt & 3;
        int cseg = t & 15, r0 = t >> 4;
#pragma unroll
        for (int rr = 0; rr < 4; ++rr) {
            int row = rr * 16 + r0;
            float4 v = *reinterpret_cast<const float4*>(
                k_w + (size_t)(ti * 64 + row) * 256 + tj * 64 + cseg * 4);
            tile[row][cseg * 4 + 0] = v.x; tile[row][cseg * 4 + 1] = v.y;
            tile[row][cseg * 4 + 2] = v.z; tile[row][cseg * 4 + 3] = v.w;
        }
        __syncthreads();
#pragma unroll
        for (int rr = 0; rr < 4; ++rr) {
            int ro = rr * 16 + r0;
            float4 v = make_float4(tile[cseg * 4 + 0][ro], tile[cseg * 4 + 1][ro],
                                   tile[cseg * 4 + 2][ro], tile[cseg * 4 + 3][ro]);
            *reinterpret_cast<float4*>(kwt + (size_t)(tj * 64 + ro) * 256 + ti * 64 + cseg * 4) = v;
        }
        return;
    }
    // ---- context MLP: block = (b, ch); rows ch*256..ch*256+255 of w2 ----
    __shared__ __align__(16) float tcs[256];
    __shared__ __align__(16) float h1[256];
    __shared__ __align__(16) float c0sh[256];
    __shared__ float sred[8];
    int mb = blk - 186, b = mb / 6, ch = mb % 6;
    int lane = t & 63, wv = t >> 6, l = t & 15, rq = t >> 4;
    tcs[t] = tc[b * 256 + t];
    __syncthreads();
#pragma unroll 4
    for (int bi = 0; bi < 16; ++bi) {
        int row = bi * 16 + rq;
        float acc = mv16(w1, 256, row, l, tcs) + b1[row];
        if (l == 0) h1[row] = gelu_exact(acc);
    }
    __syncthreads();
#pragma unroll 4
    for (int bi = 0; bi < 16; ++bi) {
        int lrow = bi * 16 + rq, row = ch * 256 + lrow;
        float a2 = mv16(w2, 256, row, l, h1) + b2[row];
        float cv = fminf(fmaxf(a2, -10.f), 10.f);
        if (l == 0) {
            clue[b * 1536 + row] = cv;
            if (ch == 0) c0sh[lrow] = cv;
        }
    }
    if (ch != 0) return;
    __syncthreads();
    // LN(clue0) -> q0
    float x0 = c0sh[t];
    float s = x0, s2 = x0 * x0;
#pragma unroll
    for (int off = 32; off > 0; off >>= 1) {
        s += __shfl_down(s, off, 64);
        s2 += __shfl_down(s2, off, 64);
    }
    if (lane == 0) { sred[wv] = s; sred[4 + wv] = s2; }
    __syncthreads();
    float mu = (sred[0] + sred[1] + sred[2] + sred[3]) * (1.f / 256.f);
    float var = (sred[4] + sred[5] + sred[6] + sred[7]) * (1.f / 256.f) - mu * mu;
    float rs = rsqrtf(var + 1e-5f);
    __syncthreads();
    tcs[t] = (x0 - mu) * rs * qn_g[t] + qn_b[t];
    __syncthreads();
#pragma unroll 4
    for (int bi = 0; bi < 16; ++bi) {
        int row = bi * 16 + rq;
        float qv = mv16(q_w, 256, row, l, tcs) + q_b[row];
        if (l == 0) qbuf[b * 256 + row] = qv;
    }
}

// ---------------- fused transpose + LN -> ft (bf16, row-major [b][n][256]) ----------
__global__ __launch_bounds__(256, 4) void k_ln(
    const float* __restrict__ features, const float* __restrict__ fn_g,
    const float* __restrict__ fn_b, unsigned short* __restrict__ ft,
    const float* __restrict__ qbuf, const float* __restrict__ kwt,
    const float* __restrict__ k_b, float* __restrict__ qpr,
    float* __restrict__ qct) {
    int tile = blockIdx.x, b = blockIdx.y, t = threadIdx.x;
    int lane = t & 63, wv = t >> 6, l = t & 15;
    __shared__ __align__(16) unsigned short A[64 * 264];   // padded rows
    __shared__ __align__(16) float redS[4][16][8];
    __shared__ __align__(16) float qs[256];
    __shared__ float sred[4];
    unsigned int* A32 = reinterpret_cast<unsigned int*>(A);

    if (tile == 64) {   // q' for step 0
        int rq = t >> 4;
        qs[t] = qbuf[b * 256 + t];
        __syncthreads();
#pragma unroll 4
        for (int bi = 0; bi < 16; ++bi) {
            int row = bi * 16 + rq;
            float qp = mv16(kwt, 256, row, l, qs);
            if (l == 0) qpr[b * 256 + row] = qp;
        }
        float ct = qs[t] * k_b[t];
#pragma unroll
        for (int off = 32; off > 0; off >>= 1) ct += __shfl_down(ct, off, 64);
        if (lane == 0) sred[wv] = ct;
        __syncthreads();
        if (t == 0) qct[b] = sred[0] + sred[1] + sred[2] + sred[3];
        return;
    }

    int n0 = tile * 64, dq = t >> 4;          // lane n-group l: n = n0 + l*4 + k
    const float* fb = features + (size_t)b * 1048576 + (size_t)dq * 16 * 4096 + n0 + l * 4;
    unsigned int u[4][8];
    float s[4] = {0, 0, 0, 0}, s2[4] = {0, 0, 0, 0};
#pragma unroll
    for (int p = 0; p < 16; ++p) {
        float4 v = *reinterpret_cast<const float4*>(fb + (size_t)p * 4096);
        s[0] += v.x; s2[0] += v.x * v.x;
        s[1] += v.y; s2[1] += v.y * v.y;
        s[2] += v.z; s2[2] += v.z * v.z;
        s[3] += v.w; s2[3] += v.w * v.w;
        unsigned int b0 = f2bf(v.x), b1_ = f2bf(v.y), b2_ = f2bf(v.z), b3_ = f2bf(v.w);
        if ((p & 1) == 0) {
            u[0][p >> 1] = b0; u[1][p >> 1] = b1_; u[2][p >> 1] = b2_; u[3][p >> 1] = b3_;
        } else {
            u[0][p >> 1] |= b0 << 16; u[1][p >> 1] |= b1_ << 16;
            u[2][p >> 1] |= b2_ << 16; u[3][p >> 1] |= b3_ << 16;
        }
    }
#pragma unroll
    for (int k = 0; k < 4; ++k) {
        s[k]  += __shfl_xor(s[k], 16, 64);  s[k]  += __shfl_xor(s[k], 32, 64);
        s2[k] += __shfl_xor(s2[k], 16, 64); s2[k] += __shfl_xor(s2[k], 32, 64);
    }
    if (lane < 16) {
        *reinterpret_cast<float4*>(&redS[wv][lane][0]) = make_float4(s[0], s[1], s[2], s[3]);
        *reinterpret_cast<float4*>(&redS[wv][lane][4]) = make_float4(s2[0], s2[1], s2[2], s2[3]);
    }
    __syncthreads();
    float mm[4], rr[4];
#pragma unroll
    for (int k = 0; k < 4; ++k) {
        float ts_ = redS[0][l][k] + redS[1][l][k] + redS[2][l][k] + redS[3][l][k];
        float t2  = redS[0][l][4 + k] + redS[1][l][4 + k] + redS[2][l][4 + k] + redS[3][l][4 + k];
        float mean = ts_ * (1.f / 256.f);
        float var = t2 * (1.f / 256.f) - mean * mean;
        mm[k] = mean; rr[k] = rsqrtf(var + 1e-5f);
    }
    float gg[16], ee[16];
#pragma unroll
    for (int j4 = 0; j4 < 4; ++j4) {
        *reinterpret_cast<float4*>(&gg[j4 * 4]) =
            *reinterpret_cast<const float4*>(fn_g + dq * 16 + j4 * 4);
        *reinterpret_cast<float4*>(&ee[j4 * 4]) =
            *reinterpret_cast<const float4*>(fn_b + dq * 16 + j4 * 4);
    }
#pragma unroll
    for (int k = 0; k < 4; ++k) {
        int rowl = l * 4 + k;
        unsigned int w[8];
#pragma unroll
        for (int j = 0; j < 8; ++j) {
            float x0 = bf2f(u[k][j]), x1 = bf2f(u[k][j] >> 16);
            unsigned int lo = f2bf((x0 - mm[k]) * rr[k] * gg[2 * j] + ee[2 * j]);
            unsigned int hi = f2bf((x1 - mm[k]) * rr[k] * gg[2 * j + 1] + ee[2 * j + 1]);
            w[j] = lo | (hi << 16);
        }
        uint4* dst = reinterpret_cast<uint4*>(&A32[rowl * 132 + dq * 8]);
        dst[0] = make_uint4(w[0], w[1], w[2], w[3]);
        dst[1] = make_uint4(w[4], w[5], w[6], w[7]);
    }
    __syncthreads();
    int ch = t & 31, rw = t >> 5;
    unsigned short* dst = ft + ((size_t)b * 4096 + n0) * 256;
#pragma unroll
    for (int ps = 0; ps < 8; ++ps) {
        int row = ps * 8 + rw;
        uint4 vv = *reinterpret_cast<const uint4*>(&A[row * 264 + ch * 8]);
        *reinterpret_cast<uint4*>(dst + (size_t)row * 256 + ch * 8) = vv;
    }
}

// ---------------- B: prologue finishes step k-1 (amap write + mask update, lmsk in
// LDS) then single pass over ft: scores + Sigma{e, e*row, e*col, e*lg, e*f} ----------
__global__ __launch_bounds__(256, 4) void k_score(
    const float* __restrict__ qpr, const float* __restrict__ qct,
    const unsigned short* __restrict__ ft, float* __restrict__ mask,
    float* __restrict__ escore, float* __restrict__ accs,
    float* __restrict__ pbuf, float* __restrict__ out_amap, int kstep) {
    int c = blockIdx.x, b = blockIdx.y, t = threadIdx.x;
    int lane = t & 63, wv = t >> 6;
    __shared__ __align__(16) float qs[256];
    __shared__ float lmsk[128];
    __shared__ __align__(16) float part2[4][256];
    __shared__ float sred[16];
    if (kstep > 0) {
        if (t < 128) {
            int n = c * 128 + t;
            float inv = 1.f / accs[(kstep - 1) * 128 + b];
            float e = escore[(size_t)b * 4096 + n];
            float m = mask[(size_t)b * 4096 + n];
            float a = fmaxf(e * inv, 1e-8f);
            out_amap[((size_t)(b * 6 + kstep - 1)) * 4096 + n] = a;
            float nm = fmaxf(m * (1.f - 0.9f * a), 1e-6f);
            mask[(size_t)b * 4096 + n] = nm;
            lmsk[t] = logf(nm);
        }
    } else if (t < 128) lmsk[t] = 0.f;
    qs[t] = qpr[b * 256 + t];
    __syncthreads();
    int l = t & 15, rg = t >> 4;        // 16 lanes per row, 16 row-groups
    float qq[16];
#pragma unroll
    for (int i = 0; i < 16; ++i) qq[i] = qs[l * 16 + i];
    float qc = qct[b];
    float acc[16];
#pragma unroll
    for (int i = 0; i < 16; ++i) acc[i] = 0.f;
    float dsum = 0.f, erow = 0.f, ecol = 0.f, elg = 0.f;
    const unsigned short* fb = ft + ((size_t)b * 4096 + c * 128) * 256 + l * 16;
#pragma unroll 2
    for (int rr = 0; rr < 8; ++rr) {
        int nl = rr * 16 + rg;
        int n = c * 128 + nl;
        const uint4* p = reinterpret_cast<const uint4*>(fb + (size_t)nl * 256);
        uint4 r0 = p[0], r1 = p[1];
        float v[16];
        v[0]  = bf2f(r0.x); v[1]  = bf2f(r0.x >> 16);
        v[2]  = bf2f(r0.y); v[3]  = bf2f(r0.y >> 16);
        v[4]  = bf2f(r0.z); v[5]  = bf2f(r0.z >> 16);
        v[6]  = bf2f(r0.w); v[7]  = bf2f(r0.w >> 16);
        v[8]  = bf2f(r1.x); v[9]  = bf2f(r1.x >> 16);
        v[10] = bf2f(r1.y); v[11] = bf2f(r1.y >> 16);
        v[12] = bf2f(r1.z); v[13] = bf2f(r1.z >> 16);
        v[14] = bf2f(r1.w); v[15] = bf2f(r1.w >> 16);
        float dot = 0.f;
#pragma unroll
        for (int i = 0; i < 16; ++i) dot += v[i] * qq[i];
        dot += __shfl_xor(dot, 1, 64);
        dot += __shfl_xor(dot, 2, 64);
        dot += __shfl_xor(dot, 4, 64);
        dot += __shfl_xor(dot, 8, 64);
        float sc = (dot + qc) * 0.0625f + lmsk[nl];
        sc = fminf(fmaxf(sc, -50.f), 50.f);
        float lg = fminf(fmaxf(sc * 2.f, -50.f), 50.f);   // /TEMP, TEMP=0.5; lg = ln e
        float e = expf(lg);
        if (l == 0) escore[(size_t)b * 4096 + n] = e;
        dsum += e; elg += e * lg;
        erow += e * (float)(n >> 6);
        ecol += e * (float)(n & 63);
#pragma unroll
        for (int i = 0; i < 16; ++i) acc[i] += e * v[i];
    }
#pragma unroll
    for (int i = 0; i < 16; ++i) {
        acc[i] += __shfl_xor(acc[i], 16, 64);
        acc[i] += __shfl_xor(acc[i], 32, 64);
    }
    if (lane < 16) {
#pragma unroll
        for (int i4 = 0; i4 < 4; ++i4)
            *reinterpret_cast<float4*>(&part2[wv][lane * 16 + i4 * 4]) =
                make_float4(acc[i4 * 4], acc[i4 * 4 + 1], acc[i4 * 4 + 2], acc[i4 * 4 + 3]);
    }
    dsum *= 0.0625f; erow *= 0.0625f; ecol *= 0.0625f; elg *= 0.0625f;
#pragma unroll
    for (int off = 32; off > 0; off >>= 1) {
        dsum += __shfl_down(dsum, off, 64);
        erow += __shfl_down(erow, off, 64);
        ecol += __shfl_down(ecol, off, 64);
        elg  += __shfl_down(elg, off, 64);
    }
    if (lane == 0) {
        sred[wv] = dsum; sred[4 + wv] = erow; sred[8 + wv] = ecol; sred[12 + wv] = elg;
    }
    __syncthreads();
    if (t == 0) {
        atomicAdd(&accs[kstep * 128 + b],      sred[0] + sred[1] + sred[2] + sred[3]);
        atomicAdd(&accs[kstep * 128 + 32 + b], sred[4] + sred[5] + sred[6] + sred[7]);
        atomicAdd(&accs[kstep * 128 + 64 + b], sred[8] + sred[9] + sred[10] + sred[11]);
        atomicAdd(&accs[kstep * 128 + 96 + b], sred[12] + sred[13] + sred[14] + sred[15]);
    }
    float sum = part2[0][t] + part2[1][t] + part2[2][t] + part2[3][t];
    pbuf[((size_t)c * 32 + b) * 256 + t] = sum;
}

// ---------------- C: per-b block: abar -> attended -> stop+centroid (step k);
// GRU -> h -> LN -> q -> q' for step k+1. bb>=32 at k==5: amap(5) writeout. ----------
__global__ void k_gru(
    const float* __restrict__ pbuf, float* __restrict__ accs,
    const float* __restrict__ escore, float* __restrict__ out_amap,
    float* __restrict__ state, const float* __restrict__ clue,
    const float* __restrict__ qn_g, const float* __restrict__ qn_b,
    const float* __restrict__ q_w, const float* __restrict__ q_b,
    const float* __restrict__ v_w, const float* __restrict__ v_b,
    const float* __restrict__ wih, const float* __restrict__ bih,
    const float* __restrict__ whh, const float* __restrict__ bhh,
    const float* __restrict__ kwt, const float* __restrict__ k_b,
    const float* __restrict__ sw1p, const float* __restrict__ sb1,
    const float* __restrict__ sw2, const float* __restrict__ sb2,
    float* __restrict__ qpr, float* __restrict__ qct,
    float* __restrict__ out_cent, float* __restrict__ out_stop, int kstep) {
    int bb = blockIdx.x, t = threadIdx.x;
    if (bb >= 32) {        // amap writeout for final step only
        if (kstep != 5) return;
        int bx = bb - 32, b = bx & 31, cc = bx >> 5;
        int n4 = (cc * 256 + t) * 4;
        float inv = 1.f / accs[5 * 128 + b];
        float4 e4 = *reinterpret_cast<const float4*>(&escore[(size_t)b * 4096 + n4]);
        *reinterpret_cast<float4*>(&out_amap[((size_t)(b * 6 + 5)) * 4096 + n4]) =
            make_float4(fmaxf(e4.x * inv, 1e-8f), fmaxf(e4.y * inv, 1e-8f),
                        fmaxf(e4.z * inv, 1e-8f), fmaxf(e4.w * inv, 1e-8f));
        return;
    }
    int b = bb;
    int lane = t & 63, wv = t >> 6, l = t & 15, rq = t >> 4;
    __shared__ __align__(16) float att[256];
    __shared__ __align__(16) float atv[256];
    __shared__ __align__(16) float st[256];
    __shared__ __align__(16) float gish[768];
    __shared__ __align__(16) float ghsh[768];
    __shared__ float sred[12];
    float S = accs[kstep * 128 + b];
    float inv = 1.f / S;
    float a = 0.f;
#pragma unroll
    for (int c2 = 0; c2 < 32; ++c2) a += pbuf[((size_t)c2 * 32 + b) * 256 + t];
    att[t] = a * inv;      // abar
    __syncthreads();
#pragma unroll 4
    for (int bi = 0; bi < 16; ++bi) {
        int row = bi * 16 + rq;
        float at = mv16(v_w, 256, row, l, att) + v_b[row];
        if (l == 0) atv[row] = at;
    }
    __syncthreads();
    // stop head + centroid out (this step)
    float elg = accs[kstep * 128 + 96 + b];
    float entv = -(elg * inv - logf(S)) * 0.12022458674074826f;   // 1/log(4096+1e-6)
    float vsum = 0.f;
#pragma unroll 4
    for (int bi = 0; bi < 8; ++bi) {
        int row = bi * 16 + rq;
        float acc = mv16(sw1p, 264, row, l, atv);
        acc += sb1[row] + entv * sw1p[row * 264 + 256];
        vsum += gelu_exact(acc) * sw2[row];
    }
    vsum *= 0.0625f;
#pragma unroll
    for (int off = 32; off > 0; off >>= 1) vsum += __shfl_down(vsum, off, 64);
    if (lane == 0) sred[wv] = vsum;
    __syncthreads();
    if (t == 0) {
        float sraw = sb2[0] + sred[0] + sred[1] + sred[2] + sred[3];
        out_stop[b * 6 + kstep] = 4.f * tanhf(sraw * 0.25f);
        out_cent[(b * 6 + kstep) * 2 + 0] = accs[kstep * 128 + 32 + b] * inv;
        out_cent[(b * 6 + kstep) * 2 + 1] = accs[kstep * 128 + 64 + b] * inv;
    }
    if (kstep == 5) return;
    // GRU
    float hprev = state[b * 256 + t];
    st[t] = hprev;
    __syncthreads();
#pragma unroll 4
    for (int bi = 0; bi < 48; ++bi) {
        int row = bi * 16 + rq;
        float gi_ = mv16(wih, 256, row, l, atv) + bih[row];
        float gh_ = mv16(whh, 256, row, l, st) + bhh[row];
        if (l == 0) { gish[row] = gi_; ghsh[row] = gh_; }
    }
    __syncthreads();
    float rr_ = 1.f / (1.f + expf(-(gish[t] + ghsh[t])));
    float zz = 1.f / (1.f + expf(-(gish[256 + t] + ghsh[256 + t])));
    float nn = tanhf(gish[512 + t] + rr_ * ghsh[512 + t]);
    float h = (1.f - zz) * nn + zz * hprev;
    state[b * 256 + t] = h;
    // LN(clue_{k+1} + h) -> q -> qct, q'
    float x = clue[((size_t)b * 6 + kstep + 1) * 256 + t] + h;
    float s = x, s2v = x * x;
#pragma unroll
    for (int off = 32; off > 0; off >>= 1) {
        s += __shfl_down(s, off, 64);
        s2v += __shfl_down(s2v, off, 64);
    }
    if (lane == 0) { sred[wv] = s; sred[4 + wv] = s2v; }
    __syncthreads();
    float mu = (sred[0] + sred[1] + sred[2] + sred[3]) * (1.f / 256.f);
    float var = (sred[4] + sred[5] + sred[6] + sred[7]) * (1.f / 256.f) - mu * mu;
    float rs = rsqrtf(var + 1e-5f);
    __syncthreads();
    att[t] = (x - mu) * rs * qn_g[t] + qn_b[t];   // qln
    __syncthreads();
#pragma unroll 4
    for (int bi = 0; bi < 16; ++bi) {
        int row = bi * 16 + rq;
        float qv = mv16(q_w, 256, row, l, att) + q_b[row];
        if (l == 0) st[row] = qv;
    }
    __syncthreads();
    float ctv = st[t] * k_b[t];
#pragma unroll
    for (int off = 32; off > 0; off >>= 1) ctv += __shfl_down(ctv, off, 64);
    if (lane == 0) sred[8 + wv] = ctv;
#pragma unroll 4
    for (int bi = 0; bi < 16; ++bi) {
        int row = bi * 16 + rq;
        float qp = mv16(kwt, 256, row, l, st);
        if (l == 0) qpr[b * 256 + row] = qp;
    }
    __syncthreads();
    if (t == 0) qct[b] = sred[8] + sred[9] + sred[10] + sred[11];
}

extern "C" void kernel_launch(void* const* d_in, const int* in_sizes, int n_in,
                              void* d_out, int out_size, void* d_ws, size_t ws_size,
                              hipStream_t stream) {
    const float* features     = (const float*)d_in[0];
    const float* task_context = (const float*)d_in[1];
    const float* ctx_w1 = (const float*)d_in[2];
    const float* ctx_b1 = (const float*)d_in[3];
    const float* ctx_w2 = (const float*)d_in[4];
    const float* ctx_b2 = (const float*)d_in[5];
    const float* q_w = (const float*)d_in[6];
    const float* q_b = (const float*)d_in[7];
    const float* k_w = (const float*)d_in[8];
    const float* k_b = (const float*)d_in[9];
    const float* v_w = (const float*)d_in[10];
    const float* v_b = (const float*)d_in[11];
    const float* qn_g = (const float*)d_in[12];
    const float* qn_b = (const float*)d_in[13];
    const float* fn_g = (const float*)d_in[14];
    const float* fn_b = (const float*)d_in[15];
    const float* stop_w1 = (const float*)d_in[16];
    const float* stop_b1 = (const float*)d_in[17];
    const float* stop_w2 = (const float*)d_in[18];
    const float* stop_b2 = (const float*)d_in[19];
    const float* gru_wih = (const float*)d_in[20];
    const float* gru_bih = (const float*)d_in[21];
    const float* gru_whh = (const float*)d_in[22];
    const float* gru_bhh = (const float*)d_in[23];

    // workspace layout (~67 MB)
    unsigned short* ft = (unsigned short*)d_ws;          // [32][4096][256] bf16
    float* kwt   = (float*)(ft + (size_t)NB * NN_ * ND); // [256][256]
    float* sw1p  = kwt + 65536;                          // [128][264]
    float* clue  = sw1p + 128 * 264;                     // [32][6][256]
    float* state = clue + NB * NK * ND;                  // [32][256]
    float* qbuf  = state + NB * ND;                      // [32][256]
    float* qpr   = qbuf + NB * ND;                       // [32][256]
    float* qct   = qpr + NB * ND;                        // [32]
    float* mask  = qct + NB;                             // [32][4096]
    float* escore= mask + NB * NN_;                      // [32][4096]
    float* accs  = escore + NB * NN_;                    // [6][4][32]: S,Erow,Ecol,Elg
    float* pbuf  = accs + NK * 4 * NB;                   // [32 c][32 b][256]

    float* out_cent = (float*)d_out;          // (B,K,2)
    float* out_amap = out_cent + NB * NK * 2; // (B,K,H,W)
    float* out_stop = out_amap + (size_t)NB * NK * NN_; // (B,K)

    k_setup<<<378, 256, 0, stream>>>(mask, accs, state, kwt, k_w, stop_w1, sw1p,
                                     task_context, ctx_w1, ctx_b1, ctx_w2, ctx_b2, clue,
                                     qn_g, qn_b, q_w, q_b, qbuf);
    k_ln<<<dim3(65, 32), 256, 0, stream>>>(features, fn_g, fn_b, ft, qbuf, kwt, k_b, qpr, qct);
    for (int k = 0; k < NK; ++k) {
        k_score<<<dim3(32, 32), 256, 0, stream>>>(qpr, qct, ft, mask, escore, accs,
                                                  pbuf, out_amap, k);
        k_gru<<<160, 256, 0, stream>>>(pbuf, accs, escore, out_amap, state, clue,
                                       qn_g, qn_b, q_w, q_b, v_w, v_b,
                                       gru_wih, gru_bih, gru_whh, gru_bhh,
                                       kwt, k_b, sw1p, stop_b1, stop_w2, stop_b2,
                                       qpr, qct, out_cent, out_stop, k);
    }
}

// Round 5
// 671.087 us; speedup vs baseline: 1.3090x; 1.2986x over previous
//
#include <hip/hip_runtime.h>
#include <hip/hip_bf16.h>

// Problem constants (B=32, D=256, H=W=64, K=6, CTX=256, TEMP=0.5)
#define NB 32
#define ND 256
#define NN_ 4096
#define NK 6

__device__ __forceinline__ float bf2f(unsigned int u) {
    union { unsigned int i; float f; } v; v.i = (u & 0xffffu) << 16; return v.f;
}
__device__ __forceinline__ unsigned short f2bf(float f) {
    __hip_bfloat16 h = __float2bfloat16(f);
    return *reinterpret_cast<unsigned short*>(&h);
}
__device__ __forceinline__ float gelu_exact(float x) {
    return 0.5f * x * (1.0f + erff(x * 0.70710678118654752f));
}

// Coalesced cooperative matvec chunk: 16 lanes per row; full row dot in all 16 lanes.
__device__ __forceinline__ float mv16(const float* __restrict__ W, int stride,
                                      int row, int l, const float* xs) {
    const float4* wr = reinterpret_cast<const float4*>(W + (size_t)row * stride + l * 16);
    const float4* xv = reinterpret_cast<const float4*>(xs + l * 16);
    float acc = 0.f;
#pragma unroll
    for (int i = 0; i < 4; ++i) {
        float4 w = wr[i], x = xv[i];
        acc += w.x * x.x + w.y * x.y + w.z * x.z + w.w * x.w;
    }
    acc += __shfl_xor(acc, 1, 64);
    acc += __shfl_xor(acc, 2, 64);
    acc += __shfl_xor(acc, 4, 64);
    acc += __shfl_xor(acc, 8, 64);
    return acc;
}

// ---------------- setup: init buffers, tiled kwt=k_w^T, sw1p pad copy,
// context MLP over 192 blocks (b x 6 row-chunks), q0 in chunk-0 blocks ----------------
__global__ void k_setup(float* __restrict__ mask, float* __restrict__ accs,
                        float* __restrict__ state, float* __restrict__ kwt,
                        const float* __restrict__ k_w,
                        const float* __restrict__ sw1, float* __restrict__ sw1p,
                        const float* __restrict__ tc, const float* __restrict__ w1,
                        const float* __restrict__ b1, const float* __restrict__ w2,
                        const float* __restrict__ b2, float* __restrict__ clue,
                        const float* __restrict__ qn_g, const float* __restrict__ qn_b,
                        const float* __restrict__ q_w, const float* __restrict__ q_b,
                        float* __restrict__ qbuf) {
    int blk = blockIdx.x, t = threadIdx.x;
    if (blk < 128) {   // mask = 1
        reinterpret_cast<float4*>(mask)[blk * 256 + t] = make_float4(1.f, 1.f, 1.f, 1.f);
        return;
    }
    if (blk == 128) {  // accs [6][4][32] = 768 floats
        if (t < 192) reinterpret_cast<float4*>(accs)[t] = make_float4(0.f, 0.f, 0.f, 0.f);
        return;
    }
    if (blk < 137) {   // state [32][256]
        reinterpret_cast<float4*>(state)[(blk - 129) * 256 + t] = make_float4(0.f, 0.f, 0.f, 0.f);
        return;
    }
    if (blk < 170) {   // sw1p [128][264] padded copy of sw1 [128][257]
        int f4 = (blk - 137) * 256 + t;
        int j = f4 * 4, row = j / 264, col = j - row * 264;
        float v[4];
#pragma unroll
        for (int e = 0; e < 4; ++e) {
            int cc = col + e;
            v[e] = (cc < 257) ? sw1[row * 257 + cc] : 0.f;
        }
        *reinterpret_cast<float4*>(sw1p + j) = make_float4(v[0], v[1], v[2], v[3]);
        return;
    }
    if (blk < 186) {   // kwt = k_w^T via 64x64 LDS tiles (coalesced both sides)
        __shared__ float tile[64][65];
        int tt = blk - 170, ti = tt >> 2, tj = tt & 3;
        int cseg = t & 15, r0 = t >> 4;
#pragma unroll
        for (int rr = 0; rr < 4; ++rr) {
            int row = rr * 16 + r0;
            float4 v = *reinterpret_cast<const float4*>(
                k_w + (size_t)(ti * 64 + row) * 256 + tj * 64 + cseg * 4);
            tile[row][cseg * 4 + 0] = v.x; tile[row][cseg * 4 + 1] = v.y;
            tile[row][cseg * 4 + 2] = v.z; tile[row][cseg * 4 + 3] = v.w;
        }
        __syncthreads();
#pragma unroll
        for (int rr = 0; rr < 4; ++rr) {
            int ro = rr * 16 + r0;
            float4 v = make_float4(tile[cseg * 4 + 0][ro], tile[cseg * 4 + 1][ro],
                                   tile[cseg * 4 + 2][ro], tile[cseg * 4 + 3][ro]);
            *reinterpret_cast<float4*>(kwt + (size_t)(tj * 64 + ro) * 256 + ti * 64 + cseg * 4) = v;
        }
        return;
    }
    // ---- context MLP: block = (b, ch); rows ch*256..ch*256+255 of w2 ----
    __shared__ __align__(16) float tcs[256];
    __shared__ __align__(16) float h1[256];
    __shared__ __align__(16) float c0sh[256];
    __shared__ float sred[8];
    int mb = blk - 186, b = mb / 6, ch = mb % 6;
    int lane = t & 63, wv = t >> 6, l = t & 15, rq = t >> 4;
    tcs[t] = tc[b * 256 + t];
    __syncthreads();
#pragma unroll 4
    for (int bi = 0; bi < 16; ++bi) {
        int row = bi * 16 + rq;
        float acc = mv16(w1, 256, row, l, tcs) + b1[row];
        if (l == 0) h1[row] = gelu_exact(acc);
    }
    __syncthreads();
#pragma unroll 4
    for (int bi = 0; bi < 16; ++bi) {
        int lrow = bi * 16 + rq, row = ch * 256 + lrow;
        float a2 = mv16(w2, 256, row, l, h1) + b2[row];
        float cv = fminf(fmaxf(a2, -10.f), 10.f);
        if (l == 0) {
            clue[b * 1536 + row] = cv;
            if (ch == 0) c0sh[lrow] = cv;
        }
    }
    if (ch != 0) return;
    __syncthreads();
    // LN(clue0) -> q0
    float x0 = c0sh[t];
    float s = x0, s2 = x0 * x0;
#pragma unroll
    for (int off = 32; off > 0; off >>= 1) {
        s += __shfl_down(s, off, 64);
        s2 += __shfl_down(s2, off, 64);
    }
    if (lane == 0) { sred[wv] = s; sred[4 + wv] = s2; }
    __syncthreads();
    float mu = (sred[0] + sred[1] + sred[2] + sred[3]) * (1.f / 256.f);
    float var = (sred[4] + sred[5] + sred[6] + sred[7]) * (1.f / 256.f) - mu * mu;
    float rs = rsqrtf(var + 1e-5f);
    __syncthreads();
    tcs[t] = (x0 - mu) * rs * qn_g[t] + qn_b[t];
    __syncthreads();
#pragma unroll 4
    for (int bi = 0; bi < 16; ++bi) {
        int row = bi * 16 + rq;
        float qv = mv16(q_w, 256, row, l, tcs) + q_b[row];
        if (l == 0) qbuf[b * 256 + row] = qv;
    }
}

// ---------------- fused transpose + LN -> ft (bf16, row-major [b][n][256]) ----------
__global__ __launch_bounds__(256, 4) void k_ln(
    const float* __restrict__ features, const float* __restrict__ fn_g,
    const float* __restrict__ fn_b, unsigned short* __restrict__ ft,
    const float* __restrict__ qbuf, const float* __restrict__ kwt,
    const float* __restrict__ k_b, float* __restrict__ qpr,
    float* __restrict__ qct) {
    int tile = blockIdx.x, b = blockIdx.y, t = threadIdx.x;
    int lane = t & 63, wv = t >> 6, l = t & 15;
    __shared__ __align__(16) unsigned short A[64 * 264];   // padded rows
    __shared__ __align__(16) float redS[4][16][8];
    __shared__ __align__(16) float qs[256];
    __shared__ float sred[4];
    unsigned int* A32 = reinterpret_cast<unsigned int*>(A);

    if (tile == 64) {   // q' for step 0
        int rq = t >> 4;
        qs[t] = qbuf[b * 256 + t];
        __syncthreads();
#pragma unroll 4
        for (int bi = 0; bi < 16; ++bi) {
            int row = bi * 16 + rq;
            float qp = mv16(kwt, 256, row, l, qs);
            if (l == 0) qpr[b * 256 + row] = qp;
        }
        float ct = qs[t] * k_b[t];
#pragma unroll
        for (int off = 32; off > 0; off >>= 1) ct += __shfl_down(ct, off, 64);
        if (lane == 0) sred[wv] = ct;
        __syncthreads();
        if (t == 0) qct[b] = sred[0] + sred[1] + sred[2] + sred[3];
        return;
    }

    int n0 = tile * 64, dq = t >> 4;          // lane n-group l: n = n0 + l*4 + k
    const float* fb = features + (size_t)b * 1048576 + (size_t)dq * 16 * 4096 + n0 + l * 4;
    unsigned int u[4][8];
    float s[4] = {0, 0, 0, 0}, s2[4] = {0, 0, 0, 0};
#pragma unroll
    for (int p = 0; p < 16; ++p) {
        float4 v = *reinterpret_cast<const float4*>(fb + (size_t)p * 4096);
        s[0] += v.x; s2[0] += v.x * v.x;
        s[1] += v.y; s2[1] += v.y * v.y;
        s[2] += v.z; s2[2] += v.z * v.z;
        s[3] += v.w; s2[3] += v.w * v.w;
        unsigned int b0 = f2bf(v.x), b1_ = f2bf(v.y), b2_ = f2bf(v.z), b3_ = f2bf(v.w);
        if ((p & 1) == 0) {
            u[0][p >> 1] = b0; u[1][p >> 1] = b1_; u[2][p >> 1] = b2_; u[3][p >> 1] = b3_;
        } else {
            u[0][p >> 1] |= b0 << 16; u[1][p >> 1] |= b1_ << 16;
            u[2][p >> 1] |= b2_ << 16; u[3][p >> 1] |= b3_ << 16;
        }
    }
#pragma unroll
    for (int k = 0; k < 4; ++k) {
        s[k]  += __shfl_xor(s[k], 16, 64);  s[k]  += __shfl_xor(s[k], 32, 64);
        s2[k] += __shfl_xor(s2[k], 16, 64); s2[k] += __shfl_xor(s2[k], 32, 64);
    }
    if (lane < 16) {
        *reinterpret_cast<float4*>(&redS[wv][lane][0]) = make_float4(s[0], s[1], s[2], s[3]);
        *reinterpret_cast<float4*>(&redS[wv][lane][4]) = make_float4(s2[0], s2[1], s2[2], s2[3]);
    }
    __syncthreads();
    float mm[4], rr[4];
#pragma unroll
    for (int k = 0; k < 4; ++k) {
        float ts_ = redS[0][l][k] + redS[1][l][k] + redS[2][l][k] + redS[3][l][k];
        float t2  = redS[0][l][4 + k] + redS[1][l][4 + k] + redS[2][l][4 + k] + redS[3][l][4 + k];
        float mean = ts_ * (1.f / 256.f);
        float var = t2 * (1.f / 256.f) - mean * mean;
        mm[k] = mean; rr[k] = rsqrtf(var + 1e-5f);
    }
    float gg[16], ee[16];
#pragma unroll
    for (int j4 = 0; j4 < 4; ++j4) {
        *reinterpret_cast<float4*>(&gg[j4 * 4]) =
            *reinterpret_cast<const float4*>(fn_g + dq * 16 + j4 * 4);
        *reinterpret_cast<float4*>(&ee[j4 * 4]) =
            *reinterpret_cast<const float4*>(fn_b + dq * 16 + j4 * 4);
    }
#pragma unroll
    for (int k = 0; k < 4; ++k) {
        int rowl = l * 4 + k;
        unsigned int w[8];
#pragma unroll
        for (int j = 0; j < 8; ++j) {
            float x0 = bf2f(u[k][j]), x1 = bf2f(u[k][j] >> 16);
            unsigned int lo = f2bf((x0 - mm[k]) * rr[k] * gg[2 * j] + ee[2 * j]);
            unsigned int hi = f2bf((x1 - mm[k]) * rr[k] * gg[2 * j + 1] + ee[2 * j + 1]);
            w[j] = lo | (hi << 16);
        }
        uint4* dst = reinterpret_cast<uint4*>(&A32[rowl * 132 + dq * 8]);
        dst[0] = make_uint4(w[0], w[1], w[2], w[3]);
        dst[1] = make_uint4(w[4], w[5], w[6], w[7]);
    }
    __syncthreads();
    int ch = t & 31, rw = t >> 5;
    unsigned short* dst = ft + ((size_t)b * 4096 + n0) * 256;
#pragma unroll
    for (int ps = 0; ps < 8; ++ps) {
        int row = ps * 8 + rw;
        uint4 vv = *reinterpret_cast<const uint4*>(&A[row * 264 + ch * 8]);
        *reinterpret_cast<uint4*>(dst + (size_t)row * 256 + ch * 8) = vv;
    }
}

// ---------------- B: prologue finishes step k-1 (amap write + mask update, lmsk in
// LDS) then single pass over ft: scores + Sigma{e, e*row, e*col, e*lg, e*f} ----------
__global__ __launch_bounds__(256, 4) void k_score(
    const float* __restrict__ qpr, const float* __restrict__ qct,
    const unsigned short* __restrict__ ft, float* __restrict__ mask,
    float* __restrict__ escore, float* __restrict__ accs,
    float* __restrict__ pbuf, float* __restrict__ out_amap, int kstep) {
    int c = blockIdx.x, b = blockIdx.y, t = threadIdx.x;
    int lane = t & 63, wv = t >> 6;
    __shared__ __align__(16) float qs[256];
    __shared__ float lmsk[128];
    __shared__ __align__(16) float part2[4][256];
    __shared__ float sred[16];
    if (kstep > 0) {
        if (t < 128) {
            int n = c * 128 + t;
            float inv = 1.f / accs[(kstep - 1) * 128 + b];
            float e = escore[(size_t)b * 4096 + n];
            float m = mask[(size_t)b * 4096 + n];
            float a = fmaxf(e * inv, 1e-8f);
            out_amap[((size_t)(b * 6 + kstep - 1)) * 4096 + n] = a;
            float nm = fmaxf(m * (1.f - 0.9f * a), 1e-6f);
            mask[(size_t)b * 4096 + n] = nm;
            lmsk[t] = logf(nm);
        }
    } else if (t < 128) lmsk[t] = 0.f;
    qs[t] = qpr[b * 256 + t];
    __syncthreads();
    int l = t & 15, rg = t >> 4;        // 16 lanes per row, 16 row-groups
    float qq[16];
#pragma unroll
    for (int i = 0; i < 16; ++i) qq[i] = qs[l * 16 + i];
    float qc = qct[b];
    float acc[16];
#pragma unroll
    for (int i = 0; i < 16; ++i) acc[i] = 0.f;
    float dsum = 0.f, erow = 0.f, ecol = 0.f, elg = 0.f;
    const unsigned short* fb = ft + ((size_t)b * 4096 + c * 128) * 256 + l * 16;
#pragma unroll 2
    for (int rr = 0; rr < 8; ++rr) {
        int nl = rr * 16 + rg;
        int n = c * 128 + nl;
        const uint4* p = reinterpret_cast<const uint4*>(fb + (size_t)nl * 256);
        uint4 r0 = p[0], r1 = p[1];
        float v[16];
        v[0]  = bf2f(r0.x); v[1]  = bf2f(r0.x >> 16);
        v[2]  = bf2f(r0.y); v[3]  = bf2f(r0.y >> 16);
        v[4]  = bf2f(r0.z); v[5]  = bf2f(r0.z >> 16);
        v[6]  = bf2f(r0.w); v[7]  = bf2f(r0.w >> 16);
        v[8]  = bf2f(r1.x); v[9]  = bf2f(r1.x >> 16);
        v[10] = bf2f(r1.y); v[11] = bf2f(r1.y >> 16);
        v[12] = bf2f(r1.z); v[13] = bf2f(r1.z >> 16);
        v[14] = bf2f(r1.w); v[15] = bf2f(r1.w >> 16);
        float dot = 0.f;
#pragma unroll
        for (int i = 0; i < 16; ++i) dot += v[i] * qq[i];
        dot += __shfl_xor(dot, 1, 64);
        dot += __shfl_xor(dot, 2, 64);
        dot += __shfl_xor(dot, 4, 64);
        dot += __shfl_xor(dot, 8, 64);
        float sc = (dot + qc) * 0.0625f + lmsk[nl];
        sc = fminf(fmaxf(sc, -50.f), 50.f);
        float lg = fminf(fmaxf(sc * 2.f, -50.f), 50.f);   // /TEMP, TEMP=0.5; lg = ln e
        float e = expf(lg);
        if (l == 0) escore[(size_t)b * 4096 + n] = e;
        dsum += e; elg += e * lg;
        erow += e * (float)(n >> 6);
        ecol += e * (float)(n & 63);
#pragma unroll
        for (int i = 0; i < 16; ++i) acc[i] += e * v[i];
    }
#pragma unroll
    for (int i = 0; i < 16; ++i) {
        acc[i] += __shfl_xor(acc[i], 16, 64);
        acc[i] += __shfl_xor(acc[i], 32, 64);
    }
    if (lane < 16) {
#pragma unroll
        for (int i4 = 0; i4 < 4; ++i4)
            *reinterpret_cast<float4*>(&part2[wv][lane * 16 + i4 * 4]) =
                make_float4(acc[i4 * 4], acc[i4 * 4 + 1], acc[i4 * 4 + 2], acc[i4 * 4 + 3]);
    }
    dsum *= 0.0625f; erow *= 0.0625f; ecol *= 0.0625f; elg *= 0.0625f;
#pragma unroll
    for (int off = 32; off > 0; off >>= 1) {
        dsum += __shfl_down(dsum, off, 64);
        erow += __shfl_down(erow, off, 64);
        ecol += __shfl_down(ecol, off, 64);
        elg  += __shfl_down(elg, off, 64);
    }
    if (lane == 0) {
        sred[wv] = dsum; sred[4 + wv] = erow; sred[8 + wv] = ecol; sred[12 + wv] = elg;
    }
    __syncthreads();
    if (t == 0) {
        atomicAdd(&accs[kstep * 128 + b],      sred[0] + sred[1] + sred[2] + sred[3]);
        atomicAdd(&accs[kstep * 128 + 32 + b], sred[4] + sred[5] + sred[6] + sred[7]);
        atomicAdd(&accs[kstep * 128 + 64 + b], sred[8] + sred[9] + sred[10] + sred[11]);
        atomicAdd(&accs[kstep * 128 + 96 + b], sred[12] + sred[13] + sred[14] + sred[15]);
    }
    float sum = part2[0][t] + part2[1][t] + part2[2][t] + part2[3][t];
    pbuf[((size_t)c * 32 + b) * 256 + t] = sum;
}

// ---------------- C: per-b block (1024 thr, 16 waves, 64 row-groups): abar ->
// attended -> stop+centroid (step k); GRU -> h -> LN -> q -> q' for step k+1.
// bb>=32 (k==5 only): amap(5) writeout. ----------
__global__ __launch_bounds__(1024, 1) void k_gru(
    const float* __restrict__ pbuf, float* __restrict__ accs,
    const float* __restrict__ escore, float* __restrict__ out_amap,
    float* __restrict__ state, const float* __restrict__ clue,
    const float* __restrict__ qn_g, const float* __restrict__ qn_b,
    const float* __restrict__ q_w, const float* __restrict__ q_b,
    const float* __restrict__ v_w, const float* __restrict__ v_b,
    const float* __restrict__ wih, const float* __restrict__ bih,
    const float* __restrict__ whh, const float* __restrict__ bhh,
    const float* __restrict__ kwt, const float* __restrict__ k_b,
    const float* __restrict__ sw1p, const float* __restrict__ sb1,
    const float* __restrict__ sw2, const float* __restrict__ sb2,
    float* __restrict__ qpr, float* __restrict__ qct,
    float* __restrict__ out_cent, float* __restrict__ out_stop, int kstep) {
    int bb = blockIdx.x, t = threadIdx.x;
    if (bb >= 32) {        // amap writeout for final step (grid=64 only at k==5)
        int b = bb - 32;
        float inv = 1.f / accs[5 * 128 + b];
        int n4 = t * 4;
        float4 e4 = *reinterpret_cast<const float4*>(&escore[(size_t)b * 4096 + n4]);
        *reinterpret_cast<float4*>(&out_amap[((size_t)(b * 6 + 5)) * 4096 + n4]) =
            make_float4(fmaxf(e4.x * inv, 1e-8f), fmaxf(e4.y * inv, 1e-8f),
                        fmaxf(e4.z * inv, 1e-8f), fmaxf(e4.w * inv, 1e-8f));
        return;
    }
    int b = bb;
    int lane = t & 63, wv = t >> 6, l = t & 15, rq = t >> 4;   // rq in [0,64)
    __shared__ __align__(16) float att[256];
    __shared__ __align__(16) float atv[256];
    __shared__ __align__(16) float st[256];
    __shared__ __align__(16) float gish[768];
    __shared__ __align__(16) float ghsh[768];
    __shared__ __align__(16) float red4[4][256];
    __shared__ float sred[16];
    float S = accs[kstep * 128 + b];
    float inv = 1.f / S;
    // pbuf reduction: thread (e=t&255, g=t>>8) sums 8 c-blocks
    {
        int e = t & 255, g = t >> 8;
        float a = 0.f;
#pragma unroll
        for (int c2 = 0; c2 < 8; ++c2)
            a += pbuf[((size_t)(g * 8 + c2) * 32 + b) * 256 + e];
        red4[g][e] = a;
    }
    __syncthreads();
    if (t < 256) att[t] = (red4[0][t] + red4[1][t] + red4[2][t] + red4[3][t]) * inv;
    __syncthreads();
    // attended = v_w @ abar + v_b (4 iters)
#pragma unroll
    for (int bi = 0; bi < 4; ++bi) {
        int row = bi * 64 + rq;
        float at = mv16(v_w, 256, row, l, att) + v_b[row];
        if (l == 0) atv[row] = at;
    }
    __syncthreads();
    // stop head + centroid (this step)
    float elg = accs[kstep * 128 + 96 + b];
    float entv = -(elg * inv - logf(S)) * 0.12022458674074826f;   // 1/log(4096+1e-6)
    float vsum = 0.f;
#pragma unroll
    for (int bi = 0; bi < 2; ++bi) {
        int row = bi * 64 + rq;
        float acc = mv16(sw1p, 264, row, l, atv);
        acc += sb1[row] + entv * sw1p[row * 264 + 256];
        vsum += gelu_exact(acc) * sw2[row];
    }
    vsum *= 0.0625f;
#pragma unroll
    for (int off = 32; off > 0; off >>= 1) vsum += __shfl_down(vsum, off, 64);
    if (lane == 0) sred[wv] = vsum;
    __syncthreads();
    if (t == 0) {
        float sraw = sb2[0];
#pragma unroll
        for (int i = 0; i < 16; ++i) sraw += sred[i];
        out_stop[b * 6 + kstep] = 4.f * tanhf(sraw * 0.25f);
        out_cent[(b * 6 + kstep) * 2 + 0] = accs[kstep * 128 + 32 + b] * inv;
        out_cent[(b * 6 + kstep) * 2 + 1] = accs[kstep * 128 + 64 + b] * inv;
    }
    if (kstep == 5) return;
    // GRU gates (12 iters covering 768 rows of wih and whh)
    if (t < 256) st[t] = state[b * 256 + t];
    __syncthreads();
#pragma unroll 4
    for (int bi = 0; bi < 12; ++bi) {
        int row = bi * 64 + rq;
        float gi_ = mv16(wih, 256, row, l, atv) + bih[row];
        float gh_ = mv16(whh, 256, row, l, st) + bhh[row];
        if (l == 0) { gish[row] = gi_; ghsh[row] = gh_; }
    }
    __syncthreads();
    // combine + LN input (t<256)
    float x = 0.f;
    if (t < 256) {
        float hprev = st[t];
        float rr_ = 1.f / (1.f + expf(-(gish[t] + ghsh[t])));
        float zz = 1.f / (1.f + expf(-(gish[256 + t] + ghsh[256 + t])));
        float nn = tanhf(gish[512 + t] + rr_ * ghsh[512 + t]);
        float h = (1.f - zz) * nn + zz * hprev;
        state[b * 256 + t] = h;
        x = clue[((size_t)b * 6 + kstep + 1) * 256 + t] + h;
    }
    float s = x, s2v = x * x;
#pragma unroll
    for (int off = 32; off > 0; off >>= 1) {
        s += __shfl_down(s, off, 64);
        s2v += __shfl_down(s2v, off, 64);
    }
    if (lane == 0 && wv < 4) { sred[wv] = s; sred[4 + wv] = s2v; }
    __syncthreads();
    float mu = (sred[0] + sred[1] + sred[2] + sred[3]) * (1.f / 256.f);
    float var = (sred[4] + sred[5] + sred[6] + sred[7]) * (1.f / 256.f) - mu * mu;
    float rs = rsqrtf(var + 1e-5f);
    __syncthreads();
    if (t < 256) att[t] = (x - mu) * rs * qn_g[t] + qn_b[t];   // qln
    __syncthreads();
    // q = q_w @ qln + q_b (4 iters) -> st
#pragma unroll
    for (int bi = 0; bi < 4; ++bi) {
        int row = bi * 64 + rq;
        float qv = mv16(q_w, 256, row, l, att) + q_b[row];
        if (l == 0) st[row] = qv;
    }
    __syncthreads();
    // qct + q' = kwt @ q (4 iters)
    float ctv = (t < 256) ? st[t] * k_b[t] : 0.f;
#pragma unroll
    for (int off = 32; off > 0; off >>= 1) ctv += __shfl_down(ctv, off, 64);
    if (lane == 0 && wv < 4) sred[8 + wv] = ctv;
#pragma unroll
    for (int bi = 0; bi < 4; ++bi) {
        int row = bi * 64 + rq;
        float qp = mv16(kwt, 256, row, l, st);
        if (l == 0) qpr[b * 256 + row] = qp;
    }
    __syncthreads();
    if (t == 0) qct[b] = sred[8] + sred[9] + sred[10] + sred[11];
}

extern "C" void kernel_launch(void* const* d_in, const int* in_sizes, int n_in,
                              void* d_out, int out_size, void* d_ws, size_t ws_size,
                              hipStream_t stream) {
    const float* features     = (const float*)d_in[0];
    const float* task_context = (const float*)d_in[1];
    const float* ctx_w1 = (const float*)d_in[2];
    const float* ctx_b1 = (const float*)d_in[3];
    const float* ctx_w2 = (const float*)d_in[4];
    const float* ctx_b2 = (const float*)d_in[5];
    const float* q_w = (const float*)d_in[6];
    const float* q_b = (const float*)d_in[7];
    const float* k_w = (const float*)d_in[8];
    const float* k_b = (const float*)d_in[9];
    const float* v_w = (const float*)d_in[10];
    const float* v_b = (const float*)d_in[11];
    const float* qn_g = (const float*)d_in[12];
    const float* qn_b = (const float*)d_in[13];
    const float* fn_g = (const float*)d_in[14];
    const float* fn_b = (const float*)d_in[15];
    const float* stop_w1 = (const float*)d_in[16];
    const float* stop_b1 = (const float*)d_in[17];
    const float* stop_w2 = (const float*)d_in[18];
    const float* stop_b2 = (const float*)d_in[19];
    const float* gru_wih = (const float*)d_in[20];
    const float* gru_bih = (const float*)d_in[21];
    const float* gru_whh = (const float*)d_in[22];
    const float* gru_bhh = (const float*)d_in[23];

    // workspace layout (~67 MB)
    unsigned short* ft = (unsigned short*)d_ws;          // [32][4096][256] bf16
    float* kwt   = (float*)(ft + (size_t)NB * NN_ * ND); // [256][256]
    float* sw1p  = kwt + 65536;                          // [128][264]
    float* clue  = sw1p + 128 * 264;                     // [32][6][256]
    float* state = clue + NB * NK * ND;                  // [32][256]
    float* qbuf  = state + NB * ND;                      // [32][256]
    float* qpr   = qbuf + NB * ND;                       // [32][256]
    float* qct   = qpr + NB * ND;                        // [32]
    float* mask  = qct + NB;                             // [32][4096]
    float* escore= mask + NB * NN_;                      // [32][4096]
    float* accs  = escore + NB * NN_;                    // [6][4][32]: S,Erow,Ecol,Elg
    float* pbuf  = accs + NK * 4 * NB;                   // [32 c][32 b][256]

    float* out_cent = (float*)d_out;          // (B,K,2)
    float* out_amap = out_cent + NB * NK * 2; // (B,K,H,W)
    float* out_stop = out_amap + (size_t)NB * NK * NN_; // (B,K)

    k_setup<<<378, 256, 0, stream>>>(mask, accs, state, kwt, k_w, stop_w1, sw1p,
                                     task_context, ctx_w1, ctx_b1, ctx_w2, ctx_b2, clue,
                                     qn_g, qn_b, q_w, q_b, qbuf);
    k_ln<<<dim3(65, 32), 256, 0, stream>>>(features, fn_g, fn_b, ft, qbuf, kwt, k_b, qpr, qct);
    for (int k = 0; k < NK; ++k) {
        k_score<<<dim3(32, 32), 256, 0, stream>>>(qpr, qct, ft, mask, escore, accs,
                                                  pbuf, out_amap, k);
        k_gru<<<(k == 5 ? 64 : 32), 1024, 0, stream>>>(pbuf, accs, escore, out_amap,
                                       state, clue, qn_g, qn_b, q_w, q_b, v_w, v_b,
                                       gru_wih, gru_bih, gru_whh, gru_bhh,
                                       kwt, k_b, sw1p, stop_b1, stop_w2, stop_b2,
                                       qpr, qct, out_cent, out_stop, k);
    }
}